// Round 6
// baseline (111.681 us; speedup 1.0000x reference)
//
#include <hip/hip_runtime.h>
#include <hip/hip_bf16.h>

// Supervised contrastive loss, B=8192, D=256, T=0.07, 100 classes.
//   prep:   z f32 -> bf16 (ws); zero sn/cls_cnt/gacc
//   bucket: per-class index lists
//   passA:  symmetric row/col sums of exp(z@z^T/T) over upper-triangle
//           128x128 tiles. 512 blocks = 32 strip-pairs x 16 splits (exactly
//           2 blocks/CU). 4 waves x (64 rows x 64 cols): A in registers
//           (reloaded <=2x per block via LDS bounce), B-tile 64KB staged
//           single-buffered via global_load_lds w16 + XOR swizzle.
//           Row-sums accumulate in regs across tiles (flush per strip);
//           col-sums flushed per off-diag tile (symmetric contribution).
//   passB:  per class (100 blocks x 8 waves): async-gather members to LDS,
//           all-pairs MFMA (bitwise-equal d to passA) -> sum_same ->
//           sum_neg = sn - sum_same; pair-loss pass; block atomics into
//           gacc[0]=sum(row_loss), gacc[1]=n_valid.
//   final:  out = gacc[0]/max(gacc[1],1)

#define BN 8192
#define DD 256
#define INV_T (1.0f / 0.07f)
#define CAPI 256
#define CAP 160

typedef __attribute__((ext_vector_type(8))) __bf16 bf16x8;
typedef __attribute__((ext_vector_type(4))) float f32x4;

typedef const __attribute__((address_space(1))) void gas_void;
typedef __attribute__((address_space(3))) void las_void;

static __device__ __forceinline__ void gld_lds16(const void* g, void* l) {
    __builtin_amdgcn_global_load_lds((gas_void*)g, (las_void*)l, 16, 0, 0);
}

static __device__ __forceinline__ unsigned short f2bf(float f) {
    unsigned int u = __builtin_bit_cast(unsigned int, f);
    u = (u + 0x7FFFu + ((u >> 16) & 1u)) >> 16;   // RNE, inputs finite
    return (unsigned short)u;
}

// ---------------- kernel 1: convert z to bf16, zero sn/cls_cnt/gacc -------
__global__ __launch_bounds__(256) void k_prep(const float* __restrict__ z,
                                              unsigned short* __restrict__ zbf,
                                              float* __restrict__ sn,
                                              int* __restrict__ cls_cnt,
                                              float* __restrict__ gacc) {
    const int gid = blockIdx.x * 256 + threadIdx.x;       // 262144 threads
    const float4* z4 = (const float4*)z;
    float4 v0 = z4[gid * 2 + 0];
    float4 v1 = z4[gid * 2 + 1];
    unsigned short r[8];
    r[0] = f2bf(v0.x); r[1] = f2bf(v0.y); r[2] = f2bf(v0.z); r[3] = f2bf(v0.w);
    r[4] = f2bf(v1.x); r[5] = f2bf(v1.y); r[6] = f2bf(v1.z); r[7] = f2bf(v1.w);
    ((uint4*)zbf)[gid] = *(const uint4*)r;
    if (gid < BN) sn[gid] = 0.f;
    if (blockIdx.x == 0) {
        if (threadIdx.x < 100) cls_cnt[threadIdx.x] = 0;
        if (threadIdx.x < 2) gacc[threadIdx.x] = 0.f;
    }
}

// ---------------- kernel 1b: bucket rows by class -------------------------
__global__ __launch_bounds__(256) void k_bucket(const int* __restrict__ labels,
                                                int* __restrict__ cls_cnt,
                                                int* __restrict__ cls_idx) {
    const int gid = blockIdx.x * 256 + threadIdx.x;
    if (gid < BN) {
        const int c = labels[gid];
        const int slot = atomicAdd(&cls_cnt[c], 1);
        if (slot < CAPI) cls_idx[c * CAPI + slot] = gid;
    }
}

// ---------------- kernel 2: symmetric tile sums of exp --------------------
// Grid 512 = 32 strip-pairs x 16 splits, 256 thr = 4 waves (2 wrow x 2 wcol),
// each wave 64 rows x 64 cols of a 128x128 tile.
__global__ __launch_bounds__(256, 2) void k_passA(const unsigned short* __restrict__ zbf,
                                                  float* __restrict__ sn) {
    __shared__ char Bb[65536];                 // one 128-row x 512B tile, swizzled
    __shared__ float cs_lds[128];

    const int tid = threadIdx.x;
    const int w = tid >> 6, lane = tid & 63;
    const int l15 = lane & 15, lk = lane >> 4;
    const int wrow = w >> 1, wcol = w & 1;
    const int p = blockIdx.x >> 4, q = blockIdx.x & 15;
    const int r1 = 63 - p, n0 = 64 - p;        // jobs: strip p (n0), then strip r1 (p+1); 65 total
    const int jlo = (65 * q) >> 4, jhi = (65 * (q + 1)) >> 4;
    const char* zb = (const char*)zbf;

    auto Jof = [&](int j) { return (j < n0) ? p + j : r1 + (j - n0); };

    auto stageTile = [&](int rowblk) {
#pragma unroll
        for (int cI = 0; cI < 16; ++cI) {
            const int s = (cI * 256 + tid) * 16;          // linear LDS dest
            const int row = s >> 9, koff = s & 511;
            gld_lds16(zb + ((size_t)(rowblk * 128 + row)) * 512 + (koff ^ ((row & 7) << 4)),
                      (char*)Bb + s);
        }
    };

    bf16x8 a[4][8];
    auto readA = [&]() {
#pragma unroll
        for (int m = 0; m < 4; ++m) {
            const int row = wrow * 64 + m * 16 + l15;
            const int sw = (row & 7) << 4;
#pragma unroll
            for (int kf = 0; kf < 8; ++kf)
                a[m][kf] = *(const bf16x8*)(Bb + row * 512 + ((lk * 16 + kf * 64) ^ sw));
        }
    };

    float snp[4][4];
#pragma unroll
    for (int m = 0; m < 4; ++m)
#pragma unroll
        for (int rr = 0; rr < 4; ++rr) snp[m][rr] = 0.f;

    auto flushRows = [&](int s) {
#pragma unroll
        for (int m = 0; m < 4; ++m)
#pragma unroll
            for (int rr = 0; rr < 4; ++rr) {
                float v = snp[m][rr];
                v += __shfl_xor(v, 1, 64);
                v += __shfl_xor(v, 2, 64);
                v += __shfl_xor(v, 4, 64);
                v += __shfl_xor(v, 8, 64);
                if (l15 == 0)
                    atomicAdd(&sn[s * 128 + wrow * 64 + m * 16 + lk * 4 + rr], v);
                snp[m][rr] = 0.f;
            }
    };

    int sCur = (jlo < n0) ? p : r1;

    // ---- A setup (LDS bounce) ----
    stageTile(sCur);
    if (tid < 128) cs_lds[tid] = 0.f;
    __syncthreads();                           // A staged
    readA();
    __syncthreads();                           // a-reads drained
    stageTile(Jof(jlo));                       // first B tile
    __syncthreads();

    for (int j = jlo; j < jhi; ++j) {
        const int Jt = Jof(j);
        const bool diag = (Jt == sCur);
        const int myrow0 = wrow * 64;
        const int mycol = wcol * 64 + l15;

#pragma unroll
        for (int n = 0; n < 4; ++n) {
            const int col = wcol * 64 + n * 16 + l15;
            const int swb = (col & 7) << 4;
            bf16x8 bfr[8];
#pragma unroll
            for (int kf = 0; kf < 8; ++kf)
                bfr[kf] = *(const bf16x8*)(Bb + col * 512 + ((lk * 16 + kf * 64) ^ swb));
            f32x4 accm[4] = {};
#pragma unroll
            for (int kf = 0; kf < 8; ++kf)
#pragma unroll
                for (int m = 0; m < 4; ++m)
                    accm[m] = __builtin_amdgcn_mfma_f32_16x16x32_bf16(a[m][kf], bfr[kf], accm[m], 0, 0, 0);
            float csn = 0.f;
#pragma unroll
            for (int m = 0; m < 4; ++m)
#pragma unroll
                for (int rr = 0; rr < 4; ++rr) {
                    float e = __expf(accm[m][rr] * INV_T);
                    if (diag && (myrow0 + m * 16 + lk * 4 + rr) == (n * 16 + mycol)) e = 0.f;
                    snp[m][rr] += e;
                    csn += e;
                }
            // col-sum over the wave's 64 rows (4 lk groups)
            csn += __shfl_xor(csn, 16, 64);
            csn += __shfl_xor(csn, 32, 64);
            if (!diag && lane < 16) atomicAdd(&cs_lds[wcol * 64 + n * 16 + l15], csn);
        }
        __syncthreads();                       // B consumed + col-sums complete
        if (!diag && tid < 128) {
            atomicAdd(&sn[Jt * 128 + tid], cs_lds[tid]);   // symmetric contribution
            cs_lds[tid] = 0.f;
        }
        if (j + 1 < jhi) {
            const int sN = (j + 1 < n0) ? p : r1;
            if (sN != sCur) {
                flushRows(sCur);
                stageTile(sN);
                __syncthreads();               // A staged
                readA();
                __syncthreads();               // a-reads drained
                sCur = sN;
            }
            stageTile(Jof(j + 1));
        }
        __syncthreads();
    }
    flushRows(sCur);
}

// ---------------- kernel 3: per-class positive pairs ----------------------
// 100 blocks x 512 thr (8 waves). Async gather, two MFMA passes, atomics
// into gacc[0] (sum row_loss) and gacc[1] (n_valid).
__global__ __launch_bounds__(512) void k_passB(const unsigned short* __restrict__ zbf,
                                               const float* __restrict__ sn,
                                               const int* __restrict__ cls_cnt,
                                               const int* __restrict__ cls_idx,
                                               float* __restrict__ gacc) {
    __shared__ char Zc[CAP * 512];             // swizzled [row][512 B]
    __shared__ int glist[CAP];
    __shared__ float snl[CAP];
    __shared__ float sums[CAP];
    __shared__ float blkL;

    const int c = blockIdx.x;
    const int tid = threadIdx.x;
    const int w = tid >> 6, lane = tid & 63;
    const int l15 = lane & 15, lk = lane >> 4;
    const char* zb = (const char*)zbf;

    const int n_c = min(cls_cnt[c], CAP);
    const int nt = (n_c + 15) >> 4;
    const int rows_p = nt * 16;

    if (tid < CAP) glist[tid] = (tid < n_c) ? cls_idx[c * CAPI + tid] : 0;
    if (tid == 0) blkL = 0.f;
    __syncthreads();

    // async gather: one wave-instr moves 2 rows (64 lanes x 16B), swizzled src
    for (int e2 = w * 2; e2 < rows_p; e2 += 16) {
        const int row = e2 + (lane >> 5);
        const int cb = (lane & 31) * 16;
        gld_lds16(zb + (size_t)glist[row] * 512 + (cb ^ ((row & 7) << 4)),
                  (char*)Zc + e2 * 512);
    }
    __syncthreads();                           // vmcnt drained by barrier

    // ---- pass 1: sum_same ----
    for (int mi = w; mi < nt; mi += 8) {
        const int rowA = mi * 16 + l15;
        const int swa = (rowA & 7) << 4;
        bf16x8 a[8];
#pragma unroll
        for (int kf = 0; kf < 8; ++kf)
            a[kf] = *(const bf16x8*)(Zc + rowA * 512 + ((lk * 16 + kf * 64) ^ swa));
        float sp[4] = {};
        for (int nj = 0; nj < nt; ++nj) {
            const int colB = nj * 16 + l15;
            const int swb = (colB & 7) << 4;
            bf16x8 b[8];
#pragma unroll
            for (int kf = 0; kf < 8; ++kf)
                b[kf] = *(const bf16x8*)(Zc + colB * 512 + ((lk * 16 + kf * 64) ^ swb));
            f32x4 acc = {};
#pragma unroll
            for (int kf = 0; kf < 8; ++kf)
                acc = __builtin_amdgcn_mfma_f32_16x16x32_bf16(a[kf], b[kf], acc, 0, 0, 0);
#pragma unroll
            for (int rr = 0; rr < 4; ++rr) {
                const int i = mi * 16 + lk * 4 + rr;
                const float e = __expf(acc[rr] * INV_T);
                sp[rr] += (colB < n_c && i != colB) ? e : 0.f;
            }
        }
#pragma unroll
        for (int rr = 0; rr < 4; ++rr) {
            float v = sp[rr];
            v += __shfl_xor(v, 1, 64);
            v += __shfl_xor(v, 2, 64);
            v += __shfl_xor(v, 4, 64);
            v += __shfl_xor(v, 8, 64);
            if (l15 == 0) sums[mi * 16 + lk * 4 + rr] = v;
        }
    }
    __syncthreads();
    if (tid < CAP) snl[tid] = (tid < n_c) ? sn[glist[tid]] - sums[tid] : 0.f;
    __syncthreads();

    // ---- pass 2: pair losses ----
    for (int mi = w; mi < nt; mi += 8) {
        const int rowA = mi * 16 + l15;
        const int swa = (rowA & 7) << 4;
        bf16x8 a[8];
#pragma unroll
        for (int kf = 0; kf < 8; ++kf)
            a[kf] = *(const bf16x8*)(Zc + rowA * 512 + ((lk * 16 + kf * 64) ^ swa));
        float sneg[4];
#pragma unroll
        for (int rr = 0; rr < 4; ++rr) {
            const int i = mi * 16 + lk * 4 + rr;
            sneg[rr] = (i < n_c) ? snl[i] : 0.f;
        }
        float sp[4] = {};
        for (int nj = 0; nj < nt; ++nj) {
            const int colB = nj * 16 + l15;
            const int swb = (colB & 7) << 4;
            bf16x8 b[8];
#pragma unroll
            for (int kf = 0; kf < 8; ++kf)
                b[kf] = *(const bf16x8*)(Zc + colB * 512 + ((lk * 16 + kf * 64) ^ swb));
            f32x4 acc = {};
#pragma unroll
            for (int kf = 0; kf < 8; ++kf)
                acc = __builtin_amdgcn_mfma_f32_16x16x32_bf16(a[kf], b[kf], acc, 0, 0, 0);
#pragma unroll
            for (int rr = 0; rr < 4; ++rr) {
                const int i = mi * 16 + lk * 4 + rr;
                const float t = log1pf(sneg[rr] * __expf(-acc[rr] * INV_T));
                sp[rr] += (colB < n_c && i != colB) ? t : 0.f;
            }
        }
#pragma unroll
        for (int rr = 0; rr < 4; ++rr) {
            float v = sp[rr];
            v += __shfl_xor(v, 1, 64);
            v += __shfl_xor(v, 2, 64);
            v += __shfl_xor(v, 4, 64);
            v += __shfl_xor(v, 8, 64);
            const int i = mi * 16 + lk * 4 + rr;
            if (l15 == 0 && i < n_c && n_c > 1)
                atomicAdd(&blkL, v / (float)(n_c - 1));
        }
    }
    __syncthreads();
    if (tid == 0 && n_c > 1) {
        atomicAdd(&gacc[0], blkL);
        atomicAdd(&gacc[1], (float)n_c);
    }
}

// ---------------- kernel 4: final scalar ----------------------------------
__global__ void k_final(const float* __restrict__ gacc, float* __restrict__ out) {
    if (threadIdx.x == 0) {
        const float L = gacc[0], V = gacc[1];
        out[0] = (V > 0.f) ? L / fmaxf(V, 1.f) : 0.f;
    }
}

extern "C" void kernel_launch(void* const* d_in, const int* in_sizes, int n_in,
                              void* d_out, int out_size, void* d_ws, size_t ws_size,
                              hipStream_t stream) {
    const float* z      = (const float*)d_in[0];
    const int*   labels = (const int*)d_in[1];
    float* out = (float*)d_out;

    char* ws = (char*)d_ws;
    // zbf 4MB | sn 32KB | cls_cnt 1KB | cls_idx 100KB | gacc 8B
    unsigned short* zbf = (unsigned short*)ws;
    size_t off = (size_t)BN * DD * sizeof(unsigned short);
    float* sn      = (float*)(ws + off);  off += BN * sizeof(float);
    int*   cls_cnt = (int*)(ws + off);    off += 1024;
    int*   cls_idx = (int*)(ws + off);    off += 100 * CAPI * sizeof(int);
    float* gacc    = (float*)(ws + off);  off += 2 * sizeof(float);

    k_prep  <<<1024, 256, 0, stream>>>(z, zbf, sn, cls_cnt, gacc);
    k_bucket<<<32, 256, 0, stream>>>(labels, cls_cnt, cls_idx);
    k_passA <<<512, 256, 0, stream>>>(zbf, sn);
    k_passB <<<100, 512, 0, stream>>>(zbf, sn, cls_cnt, cls_idx, gacc);
    k_final <<<1, 64, 0, stream>>>(gacc, out);
}